// Round 12
// baseline (341.924 us; speedup 1.0000x reference)
//
#include <hip/hip_runtime.h>
#include <hip/hip_bf16.h>
#include <stdint.h>

#define DIN 4096
#define DOUT 4096
#define BK 64
#define NT (DIN / BK)   // 64 K-tiles

typedef __attribute__((ext_vector_type(8))) short short8;
typedef __attribute__((ext_vector_type(8))) unsigned short ushort8;
typedef __attribute__((ext_vector_type(16))) float f32x16;

__device__ inline unsigned short f2bf(float f) {
    union { float f; unsigned u; } v; v.f = f;
    unsigned r = v.u + 0x7fffu + ((v.u >> 16) & 1u);   // RNE
    return (unsigned short)(r >> 16);
}

// ============ blocked workspace layout (shared by prep + GEMM) ==============
// elem offset for (R=row/256, u=ktile, kk, mt=row%256/32, s=kslice, r32, h):
//   R*1048576 + u*16384 + kk*8192 + mt*1024 + s*512 + r32*16 + h*8
// holding src[R*256 + mt*32 + r32][u*64 + kk*32 + (s*2+h)*8 .. +7].
// GEMM frag read (row=lane&31, fq=lane>>5) => base + (row*2+fq)*16B:
// 64 lanes = permutation of 64 contiguous 16B slots -> conflict-free.

// ---- prep 1: x (f32) -> blocked bf16 ----------------------------------------
__global__ void cvt_x_blocked(const float* __restrict__ x, ushort* __restrict__ xb) {
    const int t = threadIdx.x;                 // 256
    const int bx = blockIdx.x;                 // (M/256)*64
    const int R = bx >> 6, u = bx & 63;
    const int r32 = t >> 3, kcol = t & 7;      // r32 0..31
    const int kk = kcol >> 2, s = (kcol >> 1) & 1, h = kcol & 1;
    const float* src = x + ((size_t)R * 256) * DIN + u * 64 + kcol * 8;
    ushort* dst = xb + (size_t)R * 1048576 + (size_t)u * 16384
                + (size_t)kk * 8192 + s * 512 + r32 * 16 + h * 8;
#pragma unroll
    for (int j = 0; j < 8; ++j) {              // mt = j
        const float* p = src + ((size_t)(j * 32 + r32)) * DIN;
        float4 v0 = *(const float4*)p, v1 = *(const float4*)(p + 4);
        ushort8 o;
        o[0] = f2bf(v0.x); o[1] = f2bf(v0.y); o[2] = f2bf(v0.z); o[3] = f2bf(v0.w);
        o[4] = f2bf(v1.x); o[5] = f2bf(v1.y); o[6] = f2bf(v1.z); o[7] = f2bf(v1.w);
        *(ushort8*)(dst + (size_t)j * 1024) = o;
    }
}

// ---- prep 2a: Wt[e][d] = bf16(base[d][e] + c*mask[d][e]) (UNCHANGED, verified)
__global__ void make_wt_kernel(const float* __restrict__ base, const int* __restrict__ mask,
                               const float* __restrict__ coeff, ushort* __restrict__ wt) {
    __shared__ float tile[64][65];
    const float c = coeff[0];
    const int t = threadIdx.x;
    const int bd = blockIdx.x >> 6;
    const int be = blockIdx.x & 63;
    const int d0 = bd * 64, e0 = be * 64;
#pragma unroll
    for (int i = 0; i < 4; ++i) {
        int idx = i * 256 + t;
        int r = idx >> 4;
        int c4 = (idx & 15) << 2;
        const float4 bv = *(const float4*)(base + (size_t)(d0 + r) * DOUT + e0 + c4);
        const int4  mv = *(const int4*)(mask + (size_t)(d0 + r) * DOUT + e0 + c4);
        tile[r][c4 + 0] = bv.x + c * (float)mv.x;
        tile[r][c4 + 1] = bv.y + c * (float)mv.y;
        tile[r][c4 + 2] = bv.z + c * (float)mv.z;
        tile[r][c4 + 3] = bv.w + c * (float)mv.w;
    }
    __syncthreads();
#pragma unroll
    for (int i = 0; i < 8; ++i) {
        int idx = i * 256 + t;
        int r = idx >> 5;
        int p = (idx & 31) << 1;
        ushort2 o;
        o.x = f2bf(tile[p][r]);
        o.y = f2bf(tile[p + 1][r]);
        *(ushort2*)(wt + (size_t)(e0 + r) * DIN + d0 + p) = o;
    }
}

// ---- prep 2b: row-major Wt -> blocked ---------------------------------------
__global__ void reblock_w(const ushort* __restrict__ wt_rm, ushort* __restrict__ wb) {
    const int t = threadIdx.x;
    const int bx = blockIdx.x;                 // (DOUT/256)*64
    const int R = bx >> 6, u = bx & 63;
    const int r32 = t >> 3, kcol = t & 7;
    const int kk = kcol >> 2, s = (kcol >> 1) & 1, h = kcol & 1;
    const ushort* src = wt_rm + ((size_t)R * 256) * DIN + u * 64 + kcol * 8;
    ushort* dst = wb + (size_t)R * 1048576 + (size_t)u * 16384
                + (size_t)kk * 8192 + s * 512 + r32 * 16 + h * 8;
#pragma unroll
    for (int j = 0; j < 8; ++j) {
        ushort8 o = *(const ushort8*)(src + ((size_t)(j * 32 + r32)) * DIN);
        *(ushort8*)(dst + (size_t)j * 1024) = o;
    }
}

// ---- GEMM: 256x256, BK=64, r9 sync skeleton + 32x32x16 + blocked LDS --------
// r9's barrier/WAITV/stage proof carries verbatim (identical GLL counts/order,
// barrier placement). Reads are conflict-free by layout; no swizzle anywhere.

#define MFMA32(D, VA, VB) D = __builtin_amdgcn_mfma_f32_32x32x16_bf16(VA, VB, D, 0, 0, 0)

#define GLL(P, L) \
    __builtin_amdgcn_global_load_lds( \
        (const __attribute__((address_space(1))) void*)(P), \
        (__attribute__((address_space(3))) void*)(L), 16, 0, 0)

#define RDA(BUF,KK,MT,S) (*(const short8*)&lA[BUF][KK][awoff + (MT)*1024 + (S)*512])
#define RDB(BUF,KK,NN,S) (*(const short8*)&lB[BUF][KK][bwoff + (NN)*1024 + (S)*512])

#define STAGE_A(BUF,KK,OFE) { GLL(gA0 + (OFE), &lA[BUF][KK][doff]); \
                              GLL(gA1 + (OFE), &lA[BUF][KK][doff + 4096]); }
#define STAGE_B(BUF,KK,OFE) { GLL(gB0 + (OFE), &lB[BUF][KK][doff]); \
                              GLL(gB1 + (OFE), &lB[BUF][KK][doff + 4096]); }

#define WAITV(N)  asm volatile("s_waitcnt vmcnt(" #N ")" ::: "memory")
#define SBAR      __builtin_amdgcn_s_barrier()

// 8 MFMA = (2 m-tiles x 2 n-tiles) x K=32 (kslices S0,S1)
#define MFMA8(CX0,CX1,CY0,CY1) \
    MFMA32(CX0, a0s0, b0s0); MFMA32(CX1, a0s0, b1s0); \
    MFMA32(CY0, a1s0, b0s0); MFMA32(CY1, a1s0, b1s0); \
    MFMA32(CX0, a0s1, b0s1); MFMA32(CX1, a0s1, b1s1); \
    MFMA32(CY0, a1s1, b0s1); MFMA32(CY1, a1s1, b1s1);

// K-tile: 4 thin phases (r9 cadence), stage schedule r9-identical:
//  ph1: stage A.kk1(U+1)->other   ph2: stage B.kk1(U+1)
//  ph3: stage A.kk0(U+2)->this    ph4: stage B.kk0(U+2)
// vmcnt: WAITV(6) after ph1 MFMA; boundary G2?6 : NEXT?0.  OFE in elems of
// the blocked array (16384/K-tile, 8192/kk), iteration base advances 32768.
#define KTILE(BUF, G1, G2, NEXT, OFE1, OFE2) \
  { \
    short8 a0s0,a0s1,a1s0,a1s1,b0s0,b0s1,b1s0,b1s1; \
    a0s0=RDA(BUF,0,0,0); a0s1=RDA(BUF,0,0,1); a1s0=RDA(BUF,0,1,0); a1s1=RDA(BUF,0,1,1); \
    b0s0=RDB(BUF,0,0,0); b0s1=RDB(BUF,0,0,1); b1s0=RDB(BUF,0,1,0); b1s1=RDB(BUF,0,1,1); \
    if (G1) STAGE_A(1-(BUF), 1, OFE1) \
    SBAR; \
    __builtin_amdgcn_s_setprio(1); \
    MFMA8(c00,c01,c10,c11) \
    __builtin_amdgcn_s_setprio(0); \
    WAITV(6); \
    a0s0=RDA(BUF,0,2,0); a0s1=RDA(BUF,0,2,1); a1s0=RDA(BUF,0,3,0); a1s1=RDA(BUF,0,3,1); \
    if (G1) STAGE_B(1-(BUF), 1, OFE1) \
    SBAR; \
    __builtin_amdgcn_s_setprio(1); \
    MFMA8(c20,c21,c30,c31) \
    __builtin_amdgcn_s_setprio(0); \
    a0s0=RDA(BUF,1,0,0); a0s1=RDA(BUF,1,0,1); a1s0=RDA(BUF,1,1,0); a1s1=RDA(BUF,1,1,1); \
    b0s0=RDB(BUF,1,0,0); b0s1=RDB(BUF,1,0,1); b1s0=RDB(BUF,1,1,0); b1s1=RDB(BUF,1,1,1); \
    if (G2) STAGE_A(BUF, 0, OFE2) \
    SBAR; \
    __builtin_amdgcn_s_setprio(1); \
    MFMA8(c00,c01,c10,c11) \
    __builtin_amdgcn_s_setprio(0); \
    a0s0=RDA(BUF,1,2,0); a0s1=RDA(BUF,1,2,1); a1s0=RDA(BUF,1,3,0); a1s1=RDA(BUF,1,3,1); \
    if (G2) STAGE_B(BUF, 0, OFE2) \
    SBAR; \
    __builtin_amdgcn_s_setprio(1); \
    MFMA8(c20,c21,c30,c31) \
    __builtin_amdgcn_s_setprio(0); \
    if (G2)        { WAITV(6); } \
    else if (NEXT) { WAITV(0); } \
    SBAR; \
    __builtin_amdgcn_sched_barrier(0); \
  }

__global__ __launch_bounds__(512, 2) void gemm_kernel(const ushort* __restrict__ A,
                                                      const ushort* __restrict__ Bt,
                                                      float* __restrict__ C) {
    __shared__ __align__(16) ushort lA[2][2][256 * 32];
    __shared__ __align__(16) ushort lB[2][2][256 * 32];

    const int tid = threadIdx.x;
    const int lane = tid & 63;
    const int wave = tid >> 6;

    const int nbn = DOUT / 256;               // 16
    const int nwg = gridDim.x;                // 512
    int bid = blockIdx.x;
    int cpx = nwg >> 3;
    int s = (bid & 7) * cpx + (bid >> 3);     // XCD-contiguous chunks
    const int m0 = (s / nbn) * 256;
    const int n0 = (s % nbn) * 256;

    const int wr = wave >> 2;                 // 0..1 (M half: 4 m-tiles of 32)
    const int wc = wave & 3;                  // 0..3 (N quarter: 2 n-tiles)
    const int fr = lane & 31;                 // frag row/col
    const int fq = lane >> 5;                 // k-half

    // conflict-free frag offsets: (row*2 + fq) * 16B within [mt][s] group
    const int awoff = wr * 4096 + fr * 16 + fq * 8;
    const int bwoff = wc * 2048 + fr * 16 + fq * 8;
    const int doff = tid * 8;                 // linear stage dest

    const ushort* Ablk = A  + (size_t)(m0 >> 8) * 1048576;
    const ushort* Bblk = Bt + (size_t)(n0 >> 8) * 1048576;
    const ushort* gA0 = Ablk + doff;
    const ushort* gA1 = Ablk + doff + 4096;
    const ushort* gB0 = Bblk + doff;
    const ushort* gB1 = Bblk + doff + 4096;

    f32x16 c00 = {}, c01 = {}, c10 = {}, c11 = {};
    f32x16 c20 = {}, c21 = {}, c30 = {}, c31 = {};

    // prologue: tile0.kk0, tile0.kk1, tile1.kk0 (12 GLL/wave), r9-identical
    STAGE_A(0, 0, 0)      STAGE_B(0, 0, 0)
    STAGE_A(0, 1, 8192)   STAGE_B(0, 1, 8192)
    STAGE_A(1, 0, 16384)  STAGE_B(1, 0, 16384)
    WAITV(6);
    SBAR;
    __builtin_amdgcn_sched_barrier(0);

    for (int u = 0; u < NT; u += 2) {
        KTILE(0, 1, (u + 2 < NT), 1, 24576, 32768)
        KTILE(1, (u + 2 < NT), (u + 3 < NT), (u + 2 < NT), 40960, 49152)
        gA0 += 32768; gA1 += 32768; gB0 += 32768; gB1 += 32768;
    }

    // epilogue (r11-verified 32x32 C/D): col=fr, row=(r&3)+8*(r>>2)+4*fq
    const int gcb = n0 + wc * 64 + fr;
    const int grb = m0 + wr * 128 + fq * 4;
#define WRT(CT, M32, N32) \
    _Pragma("unroll") \
    for (int r = 0; r < 16; ++r) { \
        int grow = grb + (M32) * 32 + (r & 3) + 8 * (r >> 2); \
        C[(size_t)grow * DOUT + gcb + (N32) * 32] = CT[r]; \
    }
    WRT(c00, 0, 0) WRT(c01, 0, 1) WRT(c10, 1, 0) WRT(c11, 1, 1)
    WRT(c20, 2, 0) WRT(c21, 2, 1) WRT(c30, 3, 0) WRT(c31, 3, 1)
#undef WRT
}

extern "C" void kernel_launch(void* const* d_in, const int* in_sizes, int n_in,
                              void* d_out, int out_size, void* d_ws, size_t ws_size,
                              hipStream_t stream) {
    const float* x = (const float*)d_in[0];
    const float* base = (const float*)d_in[1];
    const float* coeff = (const float*)d_in[2];
    const int* mask = (const int*)d_in[3];
    float* out = (float*)d_out;

    const int M = in_sizes[0] / DIN;           // 8192
    ushort* xb = (ushort*)d_ws;                // M*DIN bf16 blocked (64 MB)
    ushort* wb = xb + (size_t)M * DIN;         // DOUT*DIN bf16 blocked (32 MB)
    ushort* wt_rm = (ushort*)d_out;            // scratch: row-major Wt (32 MB),
                                               // fully overwritten by gemm later

    cvt_x_blocked<<<(M / 256) * 64, 256, 0, stream>>>(x, xb);
    make_wt_kernel<<<(DIN / 64) * (DOUT / 64), 256, 0, stream>>>(base, mask, coeff, wt_rm);
    reblock_w<<<(DOUT / 256) * 64, 256, 0, stream>>>(wt_rm, wb);

    const int nwg = (M / 256) * (DOUT / 256);  // 512
    gemm_kernel<<<nwg, 512, 0, stream>>>(xb, wb, out);
}

// Round 13
// 336.975 us; speedup vs baseline: 1.0147x; 1.0147x over previous
//
#include <hip/hip_runtime.h>
#include <hip/hip_bf16.h>
#include <stdint.h>

#define DIN 4096
#define DOUT 4096
#define BK 64
#define NT (DIN / BK)   // 64 K-tiles

typedef __attribute__((ext_vector_type(8))) short short8;
typedef __attribute__((ext_vector_type(8))) unsigned short ushort8;
typedef __attribute__((ext_vector_type(16))) float f32x16;

__device__ inline unsigned short f2bf(float f) {
    union { float f; unsigned u; } v; v.f = f;
    unsigned r = v.u + 0x7fffu + ((v.u >> 16) & 1u);   // RNE
    return (unsigned short)(r >> 16);
}

// ============ blocked workspace layout (h-MAJOR, round-13 fix) ==============
// elem offset for (R=row/256, u=ktile, kk, mt=row%256/32, s=kslice, h, r32):
//   R*1048576 + u*16384 + kk*8192 + mt*1024 + s*512 + h*256 + r32*8
// holding src[R*256 + mt*32 + r32][u*64 + kk*32 + (s*2+h)*8 .. +7].
// GEMM frag read (row=lane&31, fq=lane>>5): byte = fq*512 + fr*16 = lane*16
// -> 64 lanes read 64 contiguous lane-ordered 16B slots: conflict-free
// (same form as the GLL write pattern). r12's r32-major variant was a
// non-lane-ordered permutation -> 4-way phase conflicts (2.5e7 measured).

// ---- prep 1: x (f32) -> blocked bf16 ----------------------------------------
__global__ void cvt_x_blocked(const float* __restrict__ x, ushort* __restrict__ xb) {
    const int t = threadIdx.x;                 // 256
    const int bx = blockIdx.x;                 // (M/256)*64
    const int R = bx >> 6, u = bx & 63;
    const int r32 = t >> 3, kcol = t & 7;      // r32 0..31
    const int kk = kcol >> 2, s = (kcol >> 1) & 1, h = kcol & 1;
    const float* src = x + ((size_t)R * 256) * DIN + u * 64 + kcol * 8;
    ushort* dst = xb + (size_t)R * 1048576 + (size_t)u * 16384
                + (size_t)kk * 8192 + s * 512 + h * 256 + r32 * 8;
#pragma unroll
    for (int j = 0; j < 8; ++j) {              // mt = j
        const float* p = src + ((size_t)(j * 32 + r32)) * DIN;
        float4 v0 = *(const float4*)p, v1 = *(const float4*)(p + 4);
        ushort8 o;
        o[0] = f2bf(v0.x); o[1] = f2bf(v0.y); o[2] = f2bf(v0.z); o[3] = f2bf(v0.w);
        o[4] = f2bf(v1.x); o[5] = f2bf(v1.y); o[6] = f2bf(v1.z); o[7] = f2bf(v1.w);
        *(ushort8*)(dst + (size_t)j * 1024) = o;
    }
}

// ---- prep 2a: Wt[e][d] = bf16(base[d][e] + c*mask[d][e]) (UNCHANGED, verified)
__global__ void make_wt_kernel(const float* __restrict__ base, const int* __restrict__ mask,
                               const float* __restrict__ coeff, ushort* __restrict__ wt) {
    __shared__ float tile[64][65];
    const float c = coeff[0];
    const int t = threadIdx.x;
    const int bd = blockIdx.x >> 6;
    const int be = blockIdx.x & 63;
    const int d0 = bd * 64, e0 = be * 64;
#pragma unroll
    for (int i = 0; i < 4; ++i) {
        int idx = i * 256 + t;
        int r = idx >> 4;
        int c4 = (idx & 15) << 2;
        const float4 bv = *(const float4*)(base + (size_t)(d0 + r) * DOUT + e0 + c4);
        const int4  mv = *(const int4*)(mask + (size_t)(d0 + r) * DOUT + e0 + c4);
        tile[r][c4 + 0] = bv.x + c * (float)mv.x;
        tile[r][c4 + 1] = bv.y + c * (float)mv.y;
        tile[r][c4 + 2] = bv.z + c * (float)mv.z;
        tile[r][c4 + 3] = bv.w + c * (float)mv.w;
    }
    __syncthreads();
#pragma unroll
    for (int i = 0; i < 8; ++i) {
        int idx = i * 256 + t;
        int r = idx >> 5;
        int p = (idx & 31) << 1;
        ushort2 o;
        o.x = f2bf(tile[p][r]);
        o.y = f2bf(tile[p + 1][r]);
        *(ushort2*)(wt + (size_t)(e0 + r) * DIN + d0 + p) = o;
    }
}

// ---- prep 2b: row-major Wt -> blocked (h-major) ------------------------------
__global__ void reblock_w(const ushort* __restrict__ wt_rm, ushort* __restrict__ wb) {
    const int t = threadIdx.x;
    const int bx = blockIdx.x;                 // (DOUT/256)*64
    const int R = bx >> 6, u = bx & 63;
    const int r32 = t >> 3, kcol = t & 7;
    const int kk = kcol >> 2, s = (kcol >> 1) & 1, h = kcol & 1;
    const ushort* src = wt_rm + ((size_t)R * 256) * DIN + u * 64 + kcol * 8;
    ushort* dst = wb + (size_t)R * 1048576 + (size_t)u * 16384
                + (size_t)kk * 8192 + s * 512 + h * 256 + r32 * 8;
#pragma unroll
    for (int j = 0; j < 8; ++j) {
        ushort8 o = *(const ushort8*)(src + ((size_t)(j * 32 + r32)) * DIN);
        *(ushort8*)(dst + (size_t)j * 1024) = o;
    }
}

// ---- GEMM: 256x256, BK=64, r9 sync skeleton + 32x32x16 + h-major blocked LDS
// r9's barrier/WAITV/stage proof carries verbatim (identical GLL counts/order,
// barrier placement). Frag reads now lane-order contiguous: conflict-free.

#define MFMA32(D, VA, VB) D = __builtin_amdgcn_mfma_f32_32x32x16_bf16(VA, VB, D, 0, 0, 0)

#define GLL(P, L) \
    __builtin_amdgcn_global_load_lds( \
        (const __attribute__((address_space(1))) void*)(P), \
        (__attribute__((address_space(3))) void*)(L), 16, 0, 0)

#define RDA(BUF,KK,MT,S) (*(const short8*)&lA[BUF][KK][awoff + (MT)*1024 + (S)*512])
#define RDB(BUF,KK,NN,S) (*(const short8*)&lB[BUF][KK][bwoff + (NN)*1024 + (S)*512])

#define STAGE_A(BUF,KK,OFE) { GLL(gA0 + (OFE), &lA[BUF][KK][doff]); \
                              GLL(gA1 + (OFE), &lA[BUF][KK][doff + 4096]); }
#define STAGE_B(BUF,KK,OFE) { GLL(gB0 + (OFE), &lB[BUF][KK][doff]); \
                              GLL(gB1 + (OFE), &lB[BUF][KK][doff + 4096]); }

#define WAITV(N)  asm volatile("s_waitcnt vmcnt(" #N ")" ::: "memory")
#define SBAR      __builtin_amdgcn_s_barrier()

// 8 MFMA = (2 m-tiles x 2 n-tiles) x K=32 (kslices S0,S1)
#define MFMA8(CX0,CX1,CY0,CY1) \
    MFMA32(CX0, a0s0, b0s0); MFMA32(CX1, a0s0, b1s0); \
    MFMA32(CY0, a1s0, b0s0); MFMA32(CY1, a1s0, b1s0); \
    MFMA32(CX0, a0s1, b0s1); MFMA32(CX1, a0s1, b1s1); \
    MFMA32(CY0, a1s1, b0s1); MFMA32(CY1, a1s1, b1s1);

// K-tile: 4 thin phases (r9 cadence), stage schedule r9-identical:
//  ph1: stage A.kk1(U+1)->other   ph2: stage B.kk1(U+1)
//  ph3: stage A.kk0(U+2)->this    ph4: stage B.kk0(U+2)
// vmcnt: WAITV(6) after ph1 MFMA; boundary G2?6 : NEXT?0.
#define KTILE(BUF, G1, G2, NEXT, OFE1, OFE2) \
  { \
    short8 a0s0,a0s1,a1s0,a1s1,b0s0,b0s1,b1s0,b1s1; \
    a0s0=RDA(BUF,0,0,0); a0s1=RDA(BUF,0,0,1); a1s0=RDA(BUF,0,1,0); a1s1=RDA(BUF,0,1,1); \
    b0s0=RDB(BUF,0,0,0); b0s1=RDB(BUF,0,0,1); b1s0=RDB(BUF,0,1,0); b1s1=RDB(BUF,0,1,1); \
    if (G1) STAGE_A(1-(BUF), 1, OFE1) \
    SBAR; \
    __builtin_amdgcn_s_setprio(1); \
    MFMA8(c00,c01,c10,c11) \
    __builtin_amdgcn_s_setprio(0); \
    WAITV(6); \
    a0s0=RDA(BUF,0,2,0); a0s1=RDA(BUF,0,2,1); a1s0=RDA(BUF,0,3,0); a1s1=RDA(BUF,0,3,1); \
    if (G1) STAGE_B(1-(BUF), 1, OFE1) \
    SBAR; \
    __builtin_amdgcn_s_setprio(1); \
    MFMA8(c20,c21,c30,c31) \
    __builtin_amdgcn_s_setprio(0); \
    a0s0=RDA(BUF,1,0,0); a0s1=RDA(BUF,1,0,1); a1s0=RDA(BUF,1,1,0); a1s1=RDA(BUF,1,1,1); \
    b0s0=RDB(BUF,1,0,0); b0s1=RDB(BUF,1,0,1); b1s0=RDB(BUF,1,1,0); b1s1=RDB(BUF,1,1,1); \
    if (G2) STAGE_A(BUF, 0, OFE2) \
    SBAR; \
    __builtin_amdgcn_s_setprio(1); \
    MFMA8(c00,c01,c10,c11) \
    __builtin_amdgcn_s_setprio(0); \
    a0s0=RDA(BUF,1,2,0); a0s1=RDA(BUF,1,2,1); a1s0=RDA(BUF,1,3,0); a1s1=RDA(BUF,1,3,1); \
    if (G2) STAGE_B(BUF, 0, OFE2) \
    SBAR; \
    __builtin_amdgcn_s_setprio(1); \
    MFMA8(c20,c21,c30,c31) \
    __builtin_amdgcn_s_setprio(0); \
    if (G2)        { WAITV(6); } \
    else if (NEXT) { WAITV(0); } \
    SBAR; \
    __builtin_amdgcn_sched_barrier(0); \
  }

__global__ __launch_bounds__(512, 2) void gemm_kernel(const ushort* __restrict__ A,
                                                      const ushort* __restrict__ Bt,
                                                      float* __restrict__ C) {
    __shared__ __align__(16) ushort lA[2][2][256 * 32];
    __shared__ __align__(16) ushort lB[2][2][256 * 32];

    const int tid = threadIdx.x;
    const int lane = tid & 63;
    const int wave = tid >> 6;

    const int nbn = DOUT / 256;               // 16
    const int nwg = gridDim.x;                // 512
    int bid = blockIdx.x;
    int cpx = nwg >> 3;
    int s = (bid & 7) * cpx + (bid >> 3);     // XCD-contiguous chunks
    const int m0 = (s / nbn) * 256;
    const int n0 = (s % nbn) * 256;

    const int wr = wave >> 2;                 // 0..1 (M half: 4 m-tiles of 32)
    const int wc = wave & 3;                  // 0..3 (N quarter: 2 n-tiles)
    const int fr = lane & 31;                 // frag row/col
    const int fq = lane >> 5;                 // k-half

    // h-major conflict-free frag offsets: byte = lane*16 within [mt][s] group
    const int awoff = wr * 4096 + fq * 256 + fr * 8;
    const int bwoff = wc * 2048 + fq * 256 + fr * 8;
    const int doff = tid * 8;                 // linear stage dest

    const ushort* Ablk = A  + (size_t)(m0 >> 8) * 1048576;
    const ushort* Bblk = Bt + (size_t)(n0 >> 8) * 1048576;
    const ushort* gA0 = Ablk + doff;
    const ushort* gA1 = Ablk + doff + 4096;
    const ushort* gB0 = Bblk + doff;
    const ushort* gB1 = Bblk + doff + 4096;

    f32x16 c00 = {}, c01 = {}, c10 = {}, c11 = {};
    f32x16 c20 = {}, c21 = {}, c30 = {}, c31 = {};

    // prologue: tile0.kk0, tile0.kk1, tile1.kk0 (12 GLL/wave), r9-identical
    STAGE_A(0, 0, 0)      STAGE_B(0, 0, 0)
    STAGE_A(0, 1, 8192)   STAGE_B(0, 1, 8192)
    STAGE_A(1, 0, 16384)  STAGE_B(1, 0, 16384)
    WAITV(6);
    SBAR;
    __builtin_amdgcn_sched_barrier(0);

    for (int u = 0; u < NT; u += 2) {
        KTILE(0, 1, (u + 2 < NT), 1, 24576, 32768)
        KTILE(1, (u + 2 < NT), (u + 3 < NT), (u + 2 < NT), 40960, 49152)
        gA0 += 32768; gA1 += 32768; gB0 += 32768; gB1 += 32768;
    }

    // epilogue (r11/r12-verified 32x32 C/D): col=fr, row=(r&3)+8*(r>>2)+4*fq
    const int gcb = n0 + wc * 64 + fr;
    const int grb = m0 + wr * 128 + fq * 4;
#define WRT(CT, M32, N32) \
    _Pragma("unroll") \
    for (int r = 0; r < 16; ++r) { \
        int grow = grb + (M32) * 32 + (r & 3) + 8 * (r >> 2); \
        C[(size_t)grow * DOUT + gcb + (N32) * 32] = CT[r]; \
    }
    WRT(c00, 0, 0) WRT(c01, 0, 1) WRT(c10, 1, 0) WRT(c11, 1, 1)
    WRT(c20, 2, 0) WRT(c21, 2, 1) WRT(c30, 3, 0) WRT(c31, 3, 1)
#undef WRT
}

extern "C" void kernel_launch(void* const* d_in, const int* in_sizes, int n_in,
                              void* d_out, int out_size, void* d_ws, size_t ws_size,
                              hipStream_t stream) {
    const float* x = (const float*)d_in[0];
    const float* base = (const float*)d_in[1];
    const float* coeff = (const float*)d_in[2];
    const int* mask = (const int*)d_in[3];
    float* out = (float*)d_out;

    const int M = in_sizes[0] / DIN;           // 8192
    ushort* xb = (ushort*)d_ws;                // M*DIN bf16 blocked (64 MB)
    ushort* wb = xb + (size_t)M * DIN;         // DOUT*DIN bf16 blocked (32 MB)
    ushort* wt_rm = (ushort*)d_out;            // scratch: row-major Wt (32 MB),
                                               // fully overwritten by gemm later

    cvt_x_blocked<<<(M / 256) * 64, 256, 0, stream>>>(x, xb);
    make_wt_kernel<<<(DIN / 64) * (DOUT / 64), 256, 0, stream>>>(base, mask, coeff, wt_rm);
    reblock_w<<<(DOUT / 256) * 64, 256, 0, stream>>>(wt_rm, wb);

    const int nwg = (M / 256) * (DOUT / 256);  // 512
    gemm_kernel<<<nwg, 512, 0, stream>>>(xb, wb, out);
}